// Round 3
// baseline (1612.701 us; speedup 1.0000x reference)
//
#include <hip/hip_runtime.h>

#define NN 4096
#define TT 12
#define BB 2
#define CC 32
#define WW 10            // T-2 windows
#define K3 12288         // 3*N
#define NCOL 640         // B*W*C
#define SA 4096.0f       // adj scale (2^12)
#define SX 1024.0f       // activation scale (2^10)
#define BM 48
#define BK 32
#define NT (K3 / BK)     // 384 k-steps

typedef _Float16 half8 __attribute__((ext_vector_type(8)));
typedef _Float16 half4_t __attribute__((ext_vector_type(4)));
typedef float floatx4 __attribute__((ext_vector_type(4)));

// ---------------- adj fp32 -> fp16 (scaled) ----------------
__global__ void k_conv_adj(const float* __restrict__ adj, _Float16* __restrict__ a16) {
    long n4 = (long)K3 * K3 / 4;
    long i = (long)blockIdx.x * blockDim.x + threadIdx.x;
    long stride = (long)gridDim.x * blockDim.x;
    const float4* src = (const float4*)adj;
    half4_t* dst = (half4_t*)a16;
    for (; i < n4; i += stride) {
        float4 v = src[i];
        half4_t h;
        h[0] = (_Float16)(v.x * SA);
        h[1] = (_Float16)(v.y * SA);
        h[2] = (_Float16)(v.z * SA);
        h[3] = (_Float16)(v.w * SA);
        dst[i] = h;
    }
}

// ---------------- build X0^T [NCOL][K3] fp16 ----------------
__global__ void k_prep(const float* __restrict__ data, const float* __restrict__ temb,
                       const float* __restrict__ semb, _Float16* __restrict__ x0t) {
    __shared__ float sb[CC][64 + 1];
    int z = blockIdx.y;                 // 0..59
    int b = z / 30; int r = z % 30; int w = r / 3; int j = r % 3;
    int t = w + j;
    int n0 = blockIdx.x * 64;
    int tid = threadIdx.x;
    for (int e = tid; e < 64 * CC; e += 256) {
        int nl = e >> 5, c = e & 31;
        float v = data[((long)(b * TT + t) * NN + n0 + nl) * CC + c]
                + temb[t * CC + c] + semb[(n0 + nl) * CC + c];
        sb[c][nl] = v;
    }
    __syncthreads();
    int bw = b * WW + w;
    for (int e = tid; e < 64 * CC; e += 256) {
        int c = e >> 6, nl = e & 63;
        x0t[(long)(bw * CC + c) * K3 + j * NN + n0 + nl] = (_Float16)sb[c][nl];
    }
}

__device__ __forceinline__ void gload_lds16(const _Float16* g, _Float16* l) {
    __builtin_amdgcn_global_load_lds(
        (const __attribute__((address_space(1))) void*)g,
        (__attribute__((address_space(3))) void*)l, 16, 0, 0);
}

// ---------------- fused GEMM (A[BMxK] @ BT[640xK]^T) + W-GEMM + GLU ----------------
// MODE 0: write next-layer X^T fp16 (scaled by SX)
// MODE 1: GLU + max(x1mid,x2mid,·) + final output layout (layer 3)
template <int MODE>
__global__ __launch_bounds__(512, 2) void k_gemm_glu(
    const _Float16* __restrict__ A, const _Float16* __restrict__ BT,
    const float* __restrict__ Wt, const float* __restrict__ bias,
    _Float16* __restrict__ outH,
    const _Float16* __restrict__ x1, const _Float16* __restrict__ x2,
    float* __restrict__ outF,
    float invS, int Mvalid)
{
    // per buffer: A tile [48][32] (1536 halves) then B tile [640][32] (20480 halves)
    __shared__ __attribute__((aligned(16))) _Float16 AB[2][22016];   // 88.0 KB
    __shared__ float WB[CC * 64 + 64];                               // 8.3 KB

    int tid = threadIdx.x;
    int lane = tid & 63, wid = tid >> 6;
    long m0 = (long)blockIdx.x * BM;

    for (int e = tid; e < CC * 64; e += 512) WB[e] = Wt[e];
    if (tid < 64) WB[CC * 64 + tid] = bias[tid];

    // staging source pointers (per-lane gather; LDS dest linear)
    int rowA = tid >> 2, kbA = tid & 3;                // valid for wid<3 (192 chunks)
    const _Float16* aSrc = A + (m0 + rowA) * (long)K3 + kbA * 8;
    const _Float16* bSrc0 = BT + (long)((0 * 512 + tid) >> 2) * K3 + ((0 * 512 + tid) & 3) * 8;
    const _Float16* bSrc1 = BT + (long)((1 * 512 + tid) >> 2) * K3 + ((1 * 512 + tid) & 3) * 8;
    const _Float16* bSrc2 = BT + (long)((2 * 512 + tid) >> 2) * K3 + ((2 * 512 + tid) & 3) * 8;
    const _Float16* bSrc3 = BT + (long)((3 * 512 + tid) >> 2) * K3 + ((3 * 512 + tid) & 3) * 8;
    const _Float16* bSrc4 = BT + (long)((4 * 512 + tid) >> 2) * K3 + ((4 * 512 + tid) & 3) * 8;

#define STAGE(bufi, tt)                                                          \
    do {                                                                         \
        long k0 = (long)(tt) * BK;                                               \
        _Float16* bp = AB[bufi];                                                 \
        gload_lds16(bSrc0 + k0, bp + 1536 + 0 * 4096 + wid * 512);               \
        gload_lds16(bSrc1 + k0, bp + 1536 + 1 * 4096 + wid * 512);               \
        gload_lds16(bSrc2 + k0, bp + 1536 + 2 * 4096 + wid * 512);               \
        gload_lds16(bSrc3 + k0, bp + 1536 + 3 * 4096 + wid * 512);               \
        gload_lds16(bSrc4 + k0, bp + 1536 + 4 * 4096 + wid * 512);               \
        if (wid < 3) gload_lds16(aSrc + k0, bp + wid * 512);                     \
    } while (0)

    floatx4 acc[3][5] = {};
    int fr = lane & 15;          // row/col within 16-frag
    int kq = lane >> 4;          // k quarter (8 halves)

    STAGE(0, 0);
    asm volatile("s_waitcnt vmcnt(0)" ::: "memory");
    __syncthreads();

    int cur = 0;
#pragma unroll 1
    for (int t = 0; t < NT; ++t) {
        if (t != NT - 1) STAGE(cur ^ 1, t + 1);
        const _Float16* P = AB[cur];
        half8 af[3], bf[5];
#pragma unroll
        for (int ms = 0; ms < 3; ++ms)
            af[ms] = *(const half8*)(P + (ms * 16 + fr) * 32 + kq * 8);
#pragma unroll
        for (int ns = 0; ns < 5; ++ns)
            bf[ns] = *(const half8*)(P + 1536 + (wid * 80 + ns * 16 + fr) * 32 + kq * 8);
#pragma unroll
        for (int ms = 0; ms < 3; ++ms)
#pragma unroll
            for (int ns = 0; ns < 5; ++ns)
                acc[ms][ns] = __builtin_amdgcn_mfma_f32_16x16x32_f16(af[ms], bf[ns], acc[ms][ns], 0, 0, 0);
        asm volatile("s_waitcnt vmcnt(0)" ::: "memory");
        __syncthreads();
        cur ^= 1;
    }

    // -------- epilogue: LDS-transpose acc, tiny W-GEMM + GLU --------
    float* scr = (float*)AB;         // reuse (61.7 KB needed <= 88 KB)
    const int SCRW = 321;            // padded stride (bank-spread)
    int rb = (lane >> 4) * 4, cb = lane & 15;

#pragma unroll 1
    for (int h = 0; h < 2; ++h) {
        __syncthreads();
        if ((wid >> 2) == h) {       // waves 4h..4h+3 own cols [h*320, h*320+320)
            int wl = wid & 3;
#pragma unroll
            for (int ms = 0; ms < 3; ++ms)
#pragma unroll
                for (int ns = 0; ns < 5; ++ns)
#pragma unroll
                    for (int i = 0; i < 4; ++i)
                        scr[(ms * 16 + rb + i) * SCRW + wl * 80 + ns * 16 + cb] = acc[ms][ns][i];
        }
        __syncthreads();
        if (tid < 480) {
            int row = tid % 48;
            int bwl = tid / 48;      // 0..9
            int bw = h * 10 + bwl;
            long m = m0 + row;
            float g[CC];
#pragma unroll
            for (int c = 0; c < CC; ++c) g[c] = scr[row * SCRW + bwl * 32 + c] * invS;
            float y[64];
#pragma unroll
            for (int o = 0; o < 64; ++o) y[o] = WB[CC * 64 + o];
#pragma unroll
            for (int c = 0; c < CC; ++c) {
                float gv = g[c];
#pragma unroll
                for (int o = 0; o < 64; ++o) y[o] = fmaf(gv, WB[c * 64 + o], y[o]);
            }
            if (MODE == 0) {
#pragma unroll
                for (int c = 0; c < CC; ++c) {
                    float r = y[c] * (1.f / (1.f + __expf(-y[c + 32])));
                    outH[(long)(bw * CC + c) * K3 + m] = (_Float16)(r * SX);
                }
            } else {
                if (m < Mvalid) {
                    float res[CC];
#pragma unroll
                    for (int c = 0; c < CC; ++c) {
                        float r = y[c] * (1.f / (1.f + __expf(-y[c + 32])));
                        float v1 = (float)x1[(long)(bw * CC + c) * K3 + NN + m] * (1.f / SX);
                        float v2 = (float)x2[(long)(bw * CC + c) * K3 + NN + m] * (1.f / SX);
                        res[c] = fmaxf(r, fmaxf(v1, v2));
                    }
                    float4* op = (float4*)(outF + ((long)bw * NN + m) * CC);
#pragma unroll
                    for (int q = 0; q < CC / 4; ++q)
                        op[q] = make_float4(res[q * 4 + 0], res[q * 4 + 1], res[q * 4 + 2], res[q * 4 + 3]);
                }
            }
        }
    }
#undef STAGE
}

extern "C" void kernel_launch(void* const* d_in, const int* in_sizes, int n_in,
                              void* d_out, int out_size, void* d_ws, size_t ws_size,
                              hipStream_t stream)
{
    const float* data = (const float*)d_in[0];
    const float* adj  = (const float*)d_in[1];
    const float* temb = (const float*)d_in[2];
    const float* semb = (const float*)d_in[3];
    const float* W0 = (const float*)d_in[4];
    const float* b0 = (const float*)d_in[5];
    const float* W1 = (const float*)d_in[6];
    const float* b1 = (const float*)d_in[7];
    const float* W2 = (const float*)d_in[8];
    const float* b2 = (const float*)d_in[9];
    float* out = (float*)d_out;
    (void)ws_size; (void)in_sizes; (void)n_in; (void)out_size;

    char* ws = (char*)d_ws;
    _Float16* A16 = (_Float16*)ws;  ws += (size_t)K3 * K3 * 2;        // 302 MB
    _Float16* X0  = (_Float16*)ws;  ws += (size_t)NCOL * K3 * 2;      // 15.7 MB
    _Float16* X1  = (_Float16*)ws;  ws += (size_t)NCOL * K3 * 2;
    _Float16* X2  = (_Float16*)ws;  ws += (size_t)NCOL * K3 * 2;

    k_conv_adj<<<4096, 256, 0, stream>>>(adj, A16);
    k_prep<<<dim3(64, 60), 256, 0, stream>>>(data, temb, semb, X0);

    // layer 1: 12288 rows, adj streamed exactly once (nt=1)
    k_gemm_glu<0><<<256, 512, 0, stream>>>(A16, X0, W0, b0, X1,
                                           nullptr, nullptr, nullptr, 1.f / SA, K3);
    // layer 2
    k_gemm_glu<0><<<256, 512, 0, stream>>>(A16, X1, W1, b1, X2,
                                           nullptr, nullptr, nullptr, 1.f / (SA * SX), K3);
    // layer 3: middle N rows of adj; fused GLU + 3-way max + final layout
    k_gemm_glu<1><<<86, 512, 0, stream>>>(A16 + (size_t)NN * K3, X2, W2, b2, nullptr,
                                          X1, X2, out, 1.f / (SA * SX), NN);
}

// Round 4
// 1323.616 us; speedup vs baseline: 1.2184x; 1.2184x over previous
//
#include <hip/hip_runtime.h>

#define NN 4096
#define TT 12
#define BB 2
#define CC 32
#define WW 10            // T-2 windows
#define K3 12288         // 3*N
#define NCOL 640         // B*W*C
#define SA 4096.0f       // adj scale (2^12)
#define SX 1024.0f       // activation scale (2^10)
#define BM 48
#define BNH 320          // N-half per block
#define BK 32
#define NT (K3 / BK)     // 384 k-steps

typedef _Float16 half8 __attribute__((ext_vector_type(8)));
typedef _Float16 half4_t __attribute__((ext_vector_type(4)));
typedef float floatx4 __attribute__((ext_vector_type(4)));

// ---------------- adj fp32 -> fp16 (scaled) ----------------
__global__ void k_conv_adj(const float* __restrict__ adj, _Float16* __restrict__ a16) {
    long n4 = (long)K3 * K3 / 4;
    long i = (long)blockIdx.x * blockDim.x + threadIdx.x;
    long stride = (long)gridDim.x * blockDim.x;
    const float4* src = (const float4*)adj;
    half4_t* dst = (half4_t*)a16;
    for (; i < n4; i += stride) {
        float4 v = src[i];
        half4_t h;
        h[0] = (_Float16)(v.x * SA);
        h[1] = (_Float16)(v.y * SA);
        h[2] = (_Float16)(v.z * SA);
        h[3] = (_Float16)(v.w * SA);
        dst[i] = h;
    }
}

// ---------------- build X0^T [NCOL][K3] fp16 ----------------
__global__ void k_prep(const float* __restrict__ data, const float* __restrict__ temb,
                       const float* __restrict__ semb, _Float16* __restrict__ x0t) {
    __shared__ float sb[CC][64 + 1];
    int z = blockIdx.y;                 // 0..59
    int b = z / 30; int r = z % 30; int w = r / 3; int j = r % 3;
    int t = w + j;
    int n0 = blockIdx.x * 64;
    int tid = threadIdx.x;
    for (int e = tid; e < 64 * CC; e += 256) {
        int nl = e >> 5, c = e & 31;
        float v = data[((long)(b * TT + t) * NN + n0 + nl) * CC + c]
                + temb[t * CC + c] + semb[(n0 + nl) * CC + c];
        sb[c][nl] = v;
    }
    __syncthreads();
    int bw = b * WW + w;
    for (int e = tid; e < 64 * CC; e += 256) {
        int c = e >> 6, nl = e & 63;
        x0t[(long)(bw * CC + c) * K3 + j * NN + n0 + nl] = (_Float16)sb[c][nl];
    }
}

__device__ __forceinline__ void gload_lds16(const _Float16* g, _Float16* l) {
    __builtin_amdgcn_global_load_lds(
        (const __attribute__((address_space(1))) void*)g,
        (__attribute__((address_space(3))) void*)l, 16, 0, 0);
}

// ---------------- fused GEMM (A[48xK] @ BT[320xK]^T) + W-GEMM + GLU ----------------
// grid = 2 * n_mtiles; each block owns an N-half (nh). 256 threads / 4 waves.
// 3-deep LDS pipeline, counted vmcnt, XOR k-chunk swizzle.
template <int MODE>
__global__ __launch_bounds__(256, 2) void k_gemm_glu(
    const _Float16* __restrict__ A, const _Float16* __restrict__ BT,
    const float* __restrict__ Wt, const float* __restrict__ bias,
    _Float16* __restrict__ outH,
    const _Float16* __restrict__ x1, const _Float16* __restrict__ x2,
    float* __restrict__ outF,
    float invS, int Mvalid)
{
    // per buffer: A [48][32] = 1536 halves, then B [320][32] = 10240 halves
    __shared__ __attribute__((aligned(16))) _Float16 AB[3][11776];   // 69.0 KB
    __shared__ float WB[CC * 64 + 64];                               // 8.3 KB

    int tid = threadIdx.x;
    int lane = tid & 63, wid = tid >> 6;

    // ---- bijective XCD-chunked block swizzle; (mt,nh) pairs contiguous per XCD
    int nblk = gridDim.x;
    int q = nblk >> 3, r = nblk & 7;
    int xcd = blockIdx.x & 7, idx = blockIdx.x >> 3;
    int lin = (xcd < r ? xcd * (q + 1) : r * (q + 1) + (xcd - r) * q) + idx;
    int mt = lin >> 1, nh = lin & 1;
    long m0 = (long)mt * BM;
    int n0 = nh * BNH;

    for (int e = tid; e < CC * 64; e += 256) WB[e] = Wt[e];
    if (tid < 64) WB[CC * 64 + tid] = bias[tid];

    // ---- staging source pointers (swizzled k-chunk in GLOBAL address; LDS linear)
    // A: 192 chunks, threads 0..191 (waves 0-2): chunk = tid -> row=tid>>2, kb=tid&3
    int rowA = tid >> 2, kbA_st = tid & 3;
    int ksA = kbA_st ^ ((rowA >> 1) & 3);
    const _Float16* aS = A + (m0 + rowA) * (long)K3 + ksA * 8;
    // B: 1280 chunks; instr i covers chunks i*256 + tid
    const _Float16* bS[5];
#pragma unroll
    for (int i = 0; i < 5; ++i) {
        int ci = i * 256 + tid;
        int row = ci >> 2, kb = ci & 3;
        int ks = kb ^ ((row >> 1) & 3);
        bS[i] = BT + (long)(n0 + row) * K3 + ks * 8;
    }

#define STAGE(bufi, kOff)                                                   \
    do {                                                                    \
        _Float16* bp = &AB[bufi][0];                                        \
        gload_lds16(bS[0] + (kOff), bp + 1536 + (0 * 256 + wid * 64) * 8);  \
        gload_lds16(bS[1] + (kOff), bp + 1536 + (1 * 256 + wid * 64) * 8);  \
        gload_lds16(bS[2] + (kOff), bp + 1536 + (2 * 256 + wid * 64) * 8);  \
        gload_lds16(bS[3] + (kOff), bp + 1536 + (3 * 256 + wid * 64) * 8);  \
        gload_lds16(bS[4] + (kOff), bp + 1536 + (4 * 256 + wid * 64) * 8);  \
        if (wid < 3) gload_lds16(aS + (kOff), bp + wid * 512);              \
    } while (0)

    // ---- fragment read offsets (halves), swizzle-matched
    int fr = lane & 15, kq = lane >> 4;
    int kbs = kq ^ ((fr >> 1) & 3);      // invariant under row += 16 / +80
    int aOff[3], bOff[5];
#pragma unroll
    for (int ms = 0; ms < 3; ++ms) aOff[ms] = (ms * 16 + fr) * 32 + kbs * 8;
#pragma unroll
    for (int ns = 0; ns < 5; ++ns) bOff[ns] = 1536 + (wid * 80 + ns * 16 + fr) * 32 + kbs * 8;

    floatx4 acc[3][5] = {};

    STAGE(0, 0);
    STAGE(1, BK);
    STAGE(2, 2 * BK);

    int cur = 0;
#pragma unroll 1
    for (int t = 0; t < NT; ++t) {
        int ahead = NT - 1 - t;
        if (wid < 3) {
            if (ahead >= 2)      asm volatile("s_waitcnt vmcnt(12)" ::: "memory");
            else if (ahead == 1) asm volatile("s_waitcnt vmcnt(6)" ::: "memory");
            else                 asm volatile("s_waitcnt vmcnt(0)" ::: "memory");
        } else {
            if (ahead >= 2)      asm volatile("s_waitcnt vmcnt(10)" ::: "memory");
            else if (ahead == 1) asm volatile("s_waitcnt vmcnt(5)" ::: "memory");
            else                 asm volatile("s_waitcnt vmcnt(0)" ::: "memory");
        }
        __builtin_amdgcn_s_barrier();            // buffer[cur] fully landed

        const _Float16* P = &AB[cur][0];
        half8 af[3], bf[5];
#pragma unroll
        for (int ms = 0; ms < 3; ++ms) af[ms] = *(const half8*)(P + aOff[ms]);
#pragma unroll
        for (int ns = 0; ns < 5; ++ns) bf[ns] = *(const half8*)(P + bOff[ns]);

        asm volatile("s_waitcnt lgkmcnt(0)" ::: "memory");
        __builtin_amdgcn_sched_barrier(0);
        __builtin_amdgcn_s_barrier();            // all waves done reading buffer[cur]

        if (t + 3 < NT) { STAGE(cur, (long)(t + 3) * BK); }
        __builtin_amdgcn_sched_barrier(0);

#pragma unroll
        for (int ms = 0; ms < 3; ++ms)
#pragma unroll
            for (int ns = 0; ns < 5; ++ns)
                acc[ms][ns] = __builtin_amdgcn_mfma_f32_16x16x32_f16(af[ms], bf[ns], acc[ms][ns], 0, 0, 0);

        cur = (cur == 2) ? 0 : cur + 1;
    }
#undef STAGE

    // -------- epilogue: LDS-transpose acc, tiny W-GEMM + GLU --------
    float* scr = (float*)AB;          // 48 x 321 floats = 61.6 KB <= 69 KB
    const int SCRW = 321;
    int rb = (lane >> 4) * 4, cb = lane & 15;

    __syncthreads();
#pragma unroll
    for (int ms = 0; ms < 3; ++ms)
#pragma unroll
        for (int ns = 0; ns < 5; ++ns)
#pragma unroll
            for (int i = 0; i < 4; ++i)
                scr[(ms * 16 + rb + i) * SCRW + wid * 80 + ns * 16 + cb] = acc[ms][ns][i];
    __syncthreads();

    for (int e = tid; e < 480; e += 256) {
        int row = e % 48;
        int bwl = e / 48;            // 0..9
        int bw = nh * 10 + bwl;
        long m = m0 + row;
        float g[CC];
#pragma unroll
        for (int c = 0; c < CC; ++c) g[c] = scr[row * SCRW + bwl * 32 + c] * invS;
        float y[64];
#pragma unroll
        for (int o = 0; o < 64; ++o) y[o] = WB[CC * 64 + o];
#pragma unroll
        for (int c = 0; c < CC; ++c) {
            float gv = g[c];
#pragma unroll
            for (int o = 0; o < 64; ++o) y[o] = fmaf(gv, WB[c * 64 + o], y[o]);
        }
        if (MODE == 0) {
#pragma unroll
            for (int c = 0; c < CC; ++c) {
                float rr = y[c] * (1.f / (1.f + __expf(-y[c + 32])));
                outH[(long)(bw * CC + c) * K3 + m] = (_Float16)(rr * SX);
            }
        } else {
            if (m < Mvalid) {
                float res[CC];
#pragma unroll
                for (int c = 0; c < CC; ++c) {
                    float rr = y[c] * (1.f / (1.f + __expf(-y[c + 32])));
                    float v1 = (float)x1[(long)(bw * CC + c) * K3 + NN + m] * (1.f / SX);
                    float v2 = (float)x2[(long)(bw * CC + c) * K3 + NN + m] * (1.f / SX);
                    res[c] = fmaxf(rr, fmaxf(v1, v2));
                }
                float4* op = (float4*)(outF + ((long)bw * NN + m) * CC);
#pragma unroll
                for (int qv = 0; qv < CC / 4; ++qv)
                    op[qv] = make_float4(res[qv * 4 + 0], res[qv * 4 + 1], res[qv * 4 + 2], res[qv * 4 + 3]);
            }
        }
    }
}

extern "C" void kernel_launch(void* const* d_in, const int* in_sizes, int n_in,
                              void* d_out, int out_size, void* d_ws, size_t ws_size,
                              hipStream_t stream)
{
    const float* data = (const float*)d_in[0];
    const float* adj  = (const float*)d_in[1];
    const float* temb = (const float*)d_in[2];
    const float* semb = (const float*)d_in[3];
    const float* W0 = (const float*)d_in[4];
    const float* b0 = (const float*)d_in[5];
    const float* W1 = (const float*)d_in[6];
    const float* b1 = (const float*)d_in[7];
    const float* W2 = (const float*)d_in[8];
    const float* b2 = (const float*)d_in[9];
    float* out = (float*)d_out;
    (void)ws_size; (void)in_sizes; (void)n_in; (void)out_size;

    char* ws = (char*)d_ws;
    _Float16* A16 = (_Float16*)ws;  ws += (size_t)K3 * K3 * 2;        // 302 MB
    _Float16* X0  = (_Float16*)ws;  ws += (size_t)NCOL * K3 * 2;      // 15.7 MB
    _Float16* X1  = (_Float16*)ws;  ws += (size_t)NCOL * K3 * 2;
    _Float16* X2  = (_Float16*)ws;  ws += (size_t)NCOL * K3 * 2;

    k_conv_adj<<<4096, 256, 0, stream>>>(adj, A16);
    k_prep<<<dim3(64, 60), 256, 0, stream>>>(data, temb, semb, X0);

    // layer 1: 256 m-tiles x 2 n-halves
    k_gemm_glu<0><<<512, 256, 0, stream>>>(A16, X0, W0, b0, X1,
                                           nullptr, nullptr, nullptr, 1.f / SA, K3);
    // layer 2
    k_gemm_glu<0><<<512, 256, 0, stream>>>(A16, X1, W1, b1, X2,
                                           nullptr, nullptr, nullptr, 1.f / (SA * SX), K3);
    // layer 3: middle N rows of adj; fused GLU + 3-way max + final layout
    k_gemm_glu<1><<<172, 256, 0, stream>>>(A16 + (size_t)NN * K3, X2, W2, b2, nullptr,
                                           X1, X2, out, 1.f / (SA * SX), NN);
}